// Round 1
// baseline (573.182 us; speedup 1.0000x reference)
//
#include <hip/hip_runtime.h>

// ---------------------------------------------------------------------------
// DisentangleMultiHeadedAttention on MI355X (gfx950), bf16 MFMA pipeline.
// Shapes: B=4, S=1024, HID=1024, HEADS=16, DH=64.  N_TOK = 4096.
// corr_a = qa (ka+kb)^T * scale ; corr_b = qb (ka+kb)^T * scale
// => single fused ks = k_a@Wa1^T + k_b@Wb1^T (K=2048 GEMM).
// ---------------------------------------------------------------------------

typedef __bf16 bf16;
typedef __bf16 bf16x4 __attribute__((ext_vector_type(4)));
typedef __bf16 bf16x8 __attribute__((ext_vector_type(8)));
typedef float  f32x4  __attribute__((ext_vector_type(4)));

#define HID_C   1024
#define S_C     1024
#define B_C     4
#define H_C     16
#define DH_C    64
#define NTOK    4096

// ---------------------------------------------------------------- convert ---
__global__ __launch_bounds__(256) void cvt_f32_bf16(const float* __restrict__ in,
                                                    bf16* __restrict__ out, int n) {
    int i = (blockIdx.x * 256 + threadIdx.x) * 4;
    if (i + 3 < n) {
        f32x4 v = *(const f32x4*)(in + i);
        bf16x4 o = __builtin_convertvector(v, bf16x4);
        *(bf16x4*)(out + i) = o;
    }
}

// ------------------------------------------------------------------- GEMM ---
// C[m,n] = sum_k A[m,k] * W[n,k]  (+ optional second source pair, + bias)
// M=4096, N=1024, K=1024 per source. Tile 128x128, BK=64, 4 waves, each wave
// computes a 64x64 sub-tile as 4x4 MFMA 16x16x32 tiles.
// mode 0: bf16 out, [B,H,S,DH]   (q / ks projections)
// mode 1: bf16 out, [B,H,DH,S]   (v projections, transposed for flash PV)
// mode 2: f32 out,  [token,HID]  (final output projection)
__global__ __launch_bounds__(256, 2)
void gemm_bt(const bf16* __restrict__ A1, const bf16* __restrict__ W1,
             const bf16* __restrict__ A2, const bf16* __restrict__ W2,
             const float* __restrict__ bias1, const float* __restrict__ bias2,
             void* __restrict__ out, int mode) {
    const int K = HID_C;
    __shared__ bf16 a_lds[128 * 72];   // pad 64->72: row stride 144B (16B-aligned)
    __shared__ bf16 w_lds[128 * 72];

    const int tid  = threadIdx.x;
    const int wave = tid >> 6, lane = tid & 63;
    const int quad = lane >> 4, l15 = lane & 15;
    const int row0 = blockIdx.y * 128;
    const int col0 = blockIdx.x * 128;
    const int wr = (wave >> 1) * 64;
    const int wc = (wave & 1) * 64;

    f32x4 acc[4][4] = {};

    const int nkb = A2 ? 32 : 16;
    for (int kb = 0; kb < nkb; ++kb) {
        const bf16* A = (kb < 16) ? A1 : A2;
        const bf16* W = (kb < 16) ? W1 : W2;
        const int k0 = (kb & 15) * 64;
        __syncthreads();
        // stage A-tile and W-tile: 128x64 bf16 = 1024 x 16B chunks each
        for (int i = 0; i < 4; ++i) {
            int c = tid + i * 256;
            int r = c >> 3, c8 = c & 7;
            uint4 va = *(const uint4*)(A + (size_t)(row0 + r) * K + k0 + c8 * 8);
            *(uint4*)(a_lds + r * 72 + c8 * 8) = va;
            uint4 vw = *(const uint4*)(W + (size_t)(col0 + r) * K + k0 + c8 * 8);
            *(uint4*)(w_lds + r * 72 + c8 * 8) = vw;
        }
        __syncthreads();
        for (int kk = 0; kk < 2; ++kk) {
            bf16x8 af[4], bw[4];
            for (int mi = 0; mi < 4; ++mi)
                af[mi] = *(const bf16x8*)(a_lds + (wr + mi * 16 + l15) * 72 + kk * 32 + quad * 8);
            for (int ni = 0; ni < 4; ++ni)
                bw[ni] = *(const bf16x8*)(w_lds + (wc + ni * 16 + l15) * 72 + kk * 32 + quad * 8);
            for (int mi = 0; mi < 4; ++mi)
                for (int ni = 0; ni < 4; ++ni)
                    acc[mi][ni] = __builtin_amdgcn_mfma_f32_16x16x32_bf16(af[mi], bw[ni], acc[mi][ni], 0, 0, 0);
        }
    }

    // epilogue.  C layout per 16x16 tile: col = lane&15, row = quad*4 + reg.
    for (int mi = 0; mi < 4; ++mi) {
        for (int ni = 0; ni < 4; ++ni) {
            int colg = col0 + wc + ni * 16 + l15;
            float bv = bias1 ? bias1[colg] : 0.f;
            if (bias2) bv += bias2[colg];
            for (int r = 0; r < 4; ++r) {
                int rowg = row0 + wr + mi * 16 + quad * 4 + r;
                float v = acc[mi][ni][r] + bv;
                if (mode == 2) {
                    ((float*)out)[(size_t)rowg * HID_C + colg] = v;
                } else {
                    int b = rowg >> 10, s = rowg & 1023;
                    int h = colg >> 6,  d = colg & 63;
                    size_t idx = (mode == 0)
                        ? ((size_t)((b * H_C + h) * S_C + s) * DH_C + d)
                        : ((size_t)((b * H_C + h) * DH_C + d) * S_C + s);
                    ((bf16*)out)[idx] = (bf16)v;
                }
            }
        }
    }
}

// -------------------------------------------------------------- attention ---
// One block = one (b,h) pair x 64 query rows; 4 waves x 16 rows each.
// Flash-style online softmax over 8 key-tiles of 128.
__global__ __launch_bounds__(256, 2)
void attn_fused(const bf16* __restrict__ qp, const bf16* __restrict__ ksp,
                const bf16* __restrict__ vTp, const int* __restrict__ mask,
                bf16* __restrict__ hout) {
    __shared__ bf16 q_lds[64 * 72];        // [qrow][d]   stride 144B
    __shared__ bf16 k_lds[128 * 72];       // [key][d]    stride 144B
    __shared__ bf16 vT_lds[64 * 136];      // [d][key]    stride 272B
    __shared__ bf16 p_lds[4 * 16 * 136];   // per-wave [qrow][key]

    const int tid  = threadIdx.x;
    const int wave = tid >> 6, lane = tid & 63;
    const int quad = lane >> 4, l15 = lane & 15;
    const int bh = blockIdx.y;
    const int b  = bh >> 4, h = bh & 15;
    const int s0 = blockIdx.x * 64;
    const float scale = 0.08838834764831845f;  // 1/sqrt(2*DH)

    // stage Q tile (64x64): 512 x 16B chunks
    const bf16* qbase = qp + ((size_t)bh * S_C + s0) * DH_C;
    for (int i = 0; i < 2; ++i) {
        int c = tid + i * 256;
        int r = c >> 3, c8 = c & 7;
        *(uint4*)(q_lds + r * 72 + c8 * 8) = *(const uint4*)(qbase + r * 64 + c8 * 8);
    }

    float mrow[4], lrow[4];
    f32x4 Oacc[4] = {};
    for (int r = 0; r < 4; ++r) { mrow[r] = -1e30f; lrow[r] = 0.f; }
    bf16* pw = p_lds + wave * (16 * 136);

    for (int kt = 0; kt < 8; ++kt) {
        __syncthreads();   // protect q_lds (1st iter) + k/vT re-use (later iters)
        const bf16* kbase = ksp + ((size_t)bh * S_C + kt * 128) * DH_C;
        for (int i = 0; i < 4; ++i) {
            int c = tid + i * 256;
            int r = c >> 3, c8 = c & 7;
            *(uint4*)(k_lds + r * 72 + c8 * 8) = *(const uint4*)(kbase + r * 64 + c8 * 8);
        }
        const bf16* vbase = vTp + (size_t)bh * DH_C * S_C + kt * 128;
        for (int i = 0; i < 4; ++i) {
            int c = tid + i * 256;
            int d = c >> 4, c8 = c & 15;
            *(uint4*)(vT_lds + d * 136 + c8 * 8) = *(const uint4*)(vbase + (size_t)d * S_C + c8 * 8);
        }
        __syncthreads();

        // --- scores: 16 q-rows x 128 keys ---
        f32x4 sacc[8] = {};
        for (int kk = 0; kk < 2; ++kk) {
            bf16x8 aq = *(const bf16x8*)(q_lds + (wave * 16 + l15) * 72 + kk * 32 + quad * 8);
            for (int ct = 0; ct < 8; ++ct) {
                bf16x8 bk = *(const bf16x8*)(k_lds + (ct * 16 + l15) * 72 + kk * 32 + quad * 8);
                sacc[ct] = __builtin_amdgcn_mfma_f32_16x16x32_bf16(aq, bk, sacc[ct], 0, 0, 0);
            }
        }
        // scale + key-padding mask
        for (int ct = 0; ct < 8; ++ct) {
            int key = kt * 128 + ct * 16 + l15;
            int mv = mask[b * S_C + key];
            for (int r = 0; r < 4; ++r) {
                float s = sacc[ct][r] * scale;
                sacc[ct][r] = mv ? s : -1e9f;
            }
        }
        // row max over 128 keys (per-lane over ct, then across 16-lane group)
        float tmax[4], tsum[4];
        for (int r = 0; r < 4; ++r) {
            float v = sacc[0][r];
            for (int ct = 1; ct < 8; ++ct) v = fmaxf(v, sacc[ct][r]);
            tmax[r] = v;
        }
        for (int off = 1; off < 16; off <<= 1)
            for (int r = 0; r < 4; ++r)
                tmax[r] = fmaxf(tmax[r], __shfl_xor(tmax[r], off, 64));
        float fac[4];
        for (int r = 0; r < 4; ++r) {
            float mn = fmaxf(mrow[r], tmax[r]);
            fac[r] = __expf(mrow[r] - mn);
            mrow[r] = mn;
        }
        // p = exp(s - m), row sums
        for (int r = 0; r < 4; ++r) tsum[r] = 0.f;
        for (int ct = 0; ct < 8; ++ct)
            for (int r = 0; r < 4; ++r) {
                float p = __expf(sacc[ct][r] - mrow[r]);
                sacc[ct][r] = p;
                tsum[r] += p;
            }
        for (int off = 1; off < 16; off <<= 1)
            for (int r = 0; r < 4; ++r)
                tsum[r] += __shfl_xor(tsum[r], off, 64);
        for (int r = 0; r < 4; ++r) lrow[r] = lrow[r] * fac[r] + tsum[r];
        for (int dt = 0; dt < 4; ++dt)
            for (int r = 0; r < 4; ++r)
                Oacc[dt][r] *= fac[r];
        // P: C-layout -> A-layout via wave-private LDS region
        for (int ct = 0; ct < 8; ++ct)
            for (int r = 0; r < 4; ++r)
                pw[(quad * 4 + r) * 136 + ct * 16 + l15] = (bf16)sacc[ct][r];
        // --- PV: O[16 x 64] += P[16 x 128] * V[128 x 64] ---
        for (int kk = 0; kk < 4; ++kk) {
            bf16x8 ap = *(const bf16x8*)(pw + l15 * 136 + kk * 32 + quad * 8);
            for (int dt = 0; dt < 4; ++dt) {
                bf16x8 bv = *(const bf16x8*)(vT_lds + (dt * 16 + l15) * 136 + kk * 32 + quad * 8);
                Oacc[dt] = __builtin_amdgcn_mfma_f32_16x16x32_bf16(ap, bv, Oacc[dt], 0, 0, 0);
            }
        }
    }

    // epilogue: hout is [token, HID] bf16, feeding the output GEMM
    for (int dt = 0; dt < 4; ++dt) {
        int feat = h * DH_C + dt * 16 + l15;
        for (int r = 0; r < 4; ++r) {
            int srow = s0 + wave * 16 + quad * 4 + r;
            float v = Oacc[dt][r] / lrow[r];
            hout[(size_t)(b * S_C + srow) * HID_C + feat] = (bf16)v;
        }
    }
}

// ----------------------------------------------------------------- launch ---
extern "C" void kernel_launch(void* const* d_in, const int* in_sizes, int n_in,
                              void* d_out, int out_size, void* d_ws, size_t ws_size,
                              hipStream_t stream) {
    const float* q_a  = (const float*)d_in[0];
    const float* k_a  = (const float*)d_in[1];
    const float* v_a  = (const float*)d_in[2];
    const float* q_b  = (const float*)d_in[3];
    const float* k_b  = (const float*)d_in[4];
    const float* v_b  = (const float*)d_in[5];
    const int*   mask = (const int*)  d_in[6];
    const float* Wa   = (const float*)d_in[7];
    const float* ba   = (const float*)d_in[8];
    const float* Wb   = (const float*)d_in[9];
    const float* bb   = (const float*)d_in[10];
    const float* Wo_a = (const float*)d_in[11];
    const float* bo_a = (const float*)d_in[12];
    const float* Wo_b = (const float*)d_in[13];
    const float* bo_b = (const float*)d_in[14];
    float* out = (float*)d_out;

    constexpr size_t ACT = (size_t)NTOK * HID_C;       // 4,194,304
    constexpr size_t W3  = 3 * (size_t)HID_C * HID_C;  // 3,145,728
    constexpr size_t W1  = (size_t)HID_C * HID_C;      // 1,048,576

    bf16* w = (bf16*)d_ws;
    bf16* bfa[6];
    for (int i = 0; i < 6; ++i) bfa[i] = w + (size_t)i * ACT;
    bf16* bfWa  = w + 6 * ACT;
    bf16* bfWb  = bfWa + W3;
    bf16* bfWoA = bfWb + W3;
    bf16* bfWoB = bfWoA + W1;
    bf16* qa_p  = bfWoB + W1;
    bf16* qb_p  = qa_p + ACT;
    bf16* ks_p  = qb_p + ACT;
    bf16* vTa   = ks_p + ACT;
    bf16* vTb   = vTa + ACT;
    bf16* ha    = vTb + ACT;
    bf16* hb    = ha + ACT;
    // total ws use: 120 MB

    // 1) fp32 -> bf16 converts
    const float* srcs[6] = {q_a, k_a, v_a, q_b, k_b, v_b};
    for (int i = 0; i < 6; ++i)
        cvt_f32_bf16<<<ACT / 1024, 256, 0, stream>>>(srcs[i], bfa[i], (int)ACT);
    cvt_f32_bf16<<<W3 / 1024, 256, 0, stream>>>(Wa, bfWa, (int)W3);
    cvt_f32_bf16<<<W3 / 1024, 256, 0, stream>>>(Wb, bfWb, (int)W3);
    cvt_f32_bf16<<<W1 / 1024, 256, 0, stream>>>(Wo_a, bfWoA, (int)W1);
    cvt_f32_bf16<<<W1 / 1024, 256, 0, stream>>>(Wo_b, bfWoB, (int)W1);

    // 2) projections
    dim3 gg(HID_C / 128, NTOK / 128);  // (8, 32)
    gemm_bt<<<gg, 256, 0, stream>>>(bfa[0], bfWa,           nullptr, nullptr,
                                    ba,        nullptr, qa_p, 0);
    gemm_bt<<<gg, 256, 0, stream>>>(bfa[3], bfWb,           nullptr, nullptr,
                                    bb,        nullptr, qb_p, 0);
    gemm_bt<<<gg, 256, 0, stream>>>(bfa[1], bfWa + W1,      bfa[4],  bfWb + W1,
                                    ba + 1024, bb + 1024, ks_p, 0);   // ks = ka + kb
    gemm_bt<<<gg, 256, 0, stream>>>(bfa[2], bfWa + 2 * W1,  nullptr, nullptr,
                                    ba + 2048, nullptr, vTa, 1);
    gemm_bt<<<gg, 256, 0, stream>>>(bfa[5], bfWb + 2 * W1,  nullptr, nullptr,
                                    bb + 2048, nullptr, vTb, 1);

    // 3) fused attention (both streams share ks)
    dim3 ga(S_C / 64, B_C * H_C);      // (16, 64)
    attn_fused<<<ga, 256, 0, stream>>>(qa_p, ks_p, vTa, mask, ha);
    attn_fused<<<ga, 256, 0, stream>>>(qb_p, ks_p, vTb, mask, hb);

    // 4) output projections -> fp32 d_out (concatenated tuple)
    gemm_bt<<<gg, 256, 0, stream>>>(ha, bfWoA, nullptr, nullptr, bo_a, nullptr,
                                    (void*)out, 2);
    gemm_bt<<<gg, 256, 0, stream>>>(hb, bfWoB, nullptr, nullptr, bo_b, nullptr,
                                    (void*)(out + (size_t)NTOK * HID_C), 2);
}

// Round 2
// 479.604 us; speedup vs baseline: 1.1951x; 1.1951x over previous
//
#include <hip/hip_runtime.h>

// ---------------------------------------------------------------------------
// DisentangleMultiHeadedAttention on MI355X (gfx950), bf16 MFMA pipeline v2.
// B=4, S=1024, HID=1024, HEADS=16, DH=64.  N_TOK=4096.
// corr_a = qa (ka+kb)^T * scale ; corr_b = qb (ka+kb)^T * scale
//   => one fused ks = k_a@Wa1^T + k_b@Wb1^T (K=2048 GEMM).
// v2: global_load_lds + XOR-swizzled LDS in GEMM; S^T-formulation flash
//     attention (2-shuffle reductions, register Q, b64 P-relayout, exp2).
// ---------------------------------------------------------------------------

typedef __bf16 bf16;
typedef __bf16 bf16x4 __attribute__((ext_vector_type(4)));
typedef __bf16 bf16x8 __attribute__((ext_vector_type(8)));
typedef float  f32x4  __attribute__((ext_vector_type(4)));

#define HID_C   1024
#define S_C     1024
#define B_C     4
#define H_C     16
#define DH_C    64
#define NTOK    4096

__device__ __forceinline__ void gl_lds16(const bf16* g, bf16* l) {
    __builtin_amdgcn_global_load_lds(
        (const __attribute__((address_space(1))) void*)g,
        (__attribute__((address_space(3))) void*)l, 16, 0, 0);
}

// ---------------------------------------------------------------- convert ---
struct CvtArgs {
    const float* src[10];
    bf16*        dst[10];
    int          cum[11];   // cumulative block counts (1024 elems per block)
};

__global__ __launch_bounds__(256) void cvt_all(CvtArgs a) {
    int blk = blockIdx.x;
    int seg = 0;
    while (blk >= a.cum[seg + 1]) ++seg;
    int i = ((blk - a.cum[seg]) * 256 + threadIdx.x) * 4;
    f32x4 v = *(const f32x4*)(a.src[seg] + i);
    *(bf16x4*)(a.dst[seg] + i) = __builtin_convertvector(v, bf16x4);
}

// ------------------------------------------------------------------- GEMM ---
// C[m,n] = sum_k A[m,k] * W[n,k]  (+ optional 2nd source pair, + bias)
// 128x128 tile, BK=64, global_load_lds(16B) staging, XOR-swizzled LDS chunks
// (LDS[row][ch] holds global chunk ch^(row&7): b128 frag reads are 2-way=free).
// mode 0: bf16 out [B,H,S,DH] | mode 1: bf16 out [B,H,DH,S] | mode 2: f32 out.
__global__ __launch_bounds__(256, 3)
void gemm_bt(const bf16* __restrict__ A1, const bf16* __restrict__ W1,
             const bf16* __restrict__ A2, const bf16* __restrict__ W2,
             const float* __restrict__ bias1, const float* __restrict__ bias2,
             void* __restrict__ out, int mode) {
    const int K = HID_C;
    __shared__ bf16 a_lds[128 * 64];
    __shared__ bf16 w_lds[128 * 64];

    const int tid  = threadIdx.x;
    const int wave = tid >> 6, lane = tid & 63;
    const int quad = lane >> 4, l15 = lane & 15;
    const int swz  = l15 & 7;
    const int row0 = blockIdx.y * 128;
    const int col0 = blockIdx.x * 128;
    const int wr = (wave >> 1) * 64;
    const int wc = (wave & 1) * 64;

    f32x4 acc[4][4] = {};

    const int nkb = A2 ? 32 : 16;
    for (int kb = 0; kb < nkb; ++kb) {
        const bf16* A = (kb < 16) ? A1 : A2;
        const bf16* W = (kb < 16) ? W1 : W2;
        const int k0 = (kb & 15) * 64;
        __syncthreads();
        // stage A-tile and W-tile: 128 rows x 8 chunks of 16B each
        for (int i = 0; i < 4; ++i) {
            int q = tid + i * 256;
            int r = q >> 3, c = q & 7;
            int gch = c ^ (r & 7);
            gl_lds16(A + (size_t)(row0 + r) * K + k0 + gch * 8, a_lds + q * 8);
            gl_lds16(W + (size_t)(col0 + r) * K + k0 + gch * 8, w_lds + q * 8);
        }
        __syncthreads();
        for (int kk = 0; kk < 2; ++kk) {
            const int ch = ((kk * 4 + quad) ^ swz) * 8;
            bf16x8 af[4], bw[4];
            for (int mi = 0; mi < 4; ++mi)
                af[mi] = *(const bf16x8*)(a_lds + (wr + mi * 16 + l15) * 64 + ch);
            for (int ni = 0; ni < 4; ++ni)
                bw[ni] = *(const bf16x8*)(w_lds + (wc + ni * 16 + l15) * 64 + ch);
            for (int mi = 0; mi < 4; ++mi)
                for (int ni = 0; ni < 4; ++ni)
                    acc[mi][ni] = __builtin_amdgcn_mfma_f32_16x16x32_bf16(af[mi], bw[ni], acc[mi][ni], 0, 0, 0);
        }
    }

    // epilogue.  C layout per 16x16 tile: col(n) = lane&15, row(m) = quad*4+reg.
    for (int mi = 0; mi < 4; ++mi) {
        for (int ni = 0; ni < 4; ++ni) {
            int colg = col0 + wc + ni * 16 + l15;
            float bv = bias1 ? bias1[colg] : 0.f;
            if (bias2) bv += bias2[colg];
            for (int r = 0; r < 4; ++r) {
                int rowg = row0 + wr + mi * 16 + quad * 4 + r;
                float v = acc[mi][ni][r] + bv;
                if (mode == 2) {
                    ((float*)out)[(size_t)rowg * HID_C + colg] = v;
                } else {
                    int b = rowg >> 10, s = rowg & 1023;
                    int h = colg >> 6,  d = colg & 63;
                    size_t idx = (mode == 0)
                        ? ((size_t)((b * H_C + h) * S_C + s) * DH_C + d)
                        : ((size_t)((b * H_C + h) * DH_C + d) * S_C + s);
                    ((bf16*)out)[idx] = (bf16)v;
                }
            }
        }
    }
}

// -------------------------------------------------------------- attention ---
// S^T formulation: S^T = K Q^T (A=K, B=Q), O^T = V^T P^T (A=V^T, B=P^T).
// Block = 128 q-rows x one (b,h) x one stream (blockIdx.z); 4 waves x 32 rows.
// 8 key-tiles of 128.  Softmax in log2 domain, mask as additive LDS table.
__global__ __launch_bounds__(256, 3)
void attn_fused(const bf16* __restrict__ qp_a, const bf16* __restrict__ qp_b,
                const bf16* __restrict__ ksp,
                const bf16* __restrict__ vT_a, const bf16* __restrict__ vT_b,
                const int* __restrict__ mask,
                bf16* __restrict__ ho_a, bf16* __restrict__ ho_b) {
    __shared__ bf16  k_lds[128 * 64];     // [key][d], XOR-swizzled chunks
    __shared__ bf16  vT_lds[64 * 128];    // [d][key], XOR-swizzled chunks
    __shared__ float madd[1024];          // 0 or -1e9 per key (log2 domain)
    __shared__ bf16  p_lds[4 * 32 * 40];  // per-wave [qrow][key32] pad->40

    const int tid  = threadIdx.x;
    const int wave = tid >> 6, lane = tid & 63;
    const int quad = lane >> 4, l15 = lane & 15;
    const int swz  = l15 & 7;
    const int bh = blockIdx.y;
    const int b  = bh >> 4, h = bh & 15;
    const int s0 = blockIdx.x * 128;
    const bf16* qp  = blockIdx.z ? qp_b : qp_a;
    const bf16* vTp = blockIdx.z ? vT_b : vT_a;
    bf16*       hout = blockIdx.z ? ho_b : ho_a;
    // scale * log2(e): softmax computed with exp2
    const float SC2 = 0.08838834764831845f * 1.4426950408889634f;

    // mask -> additive table (any huge negative works in log2 domain too)
    {
        int4 mv = *(const int4*)(mask + b * S_C + tid * 4);
        f32x4 md;
        md[0] = mv.x ? 0.f : -1e9f;
        md[1] = mv.y ? 0.f : -1e9f;
        md[2] = mv.z ? 0.f : -1e9f;
        md[3] = mv.w ? 0.f : -1e9f;
        *(f32x4*)(madd + tid * 4) = md;
    }

    // Q B-fragments straight from global, live in registers all kernel
    bf16x8 qf[2][2];
    for (int qt = 0; qt < 2; ++qt)
        for (int kk = 0; kk < 2; ++kk)
            qf[qt][kk] = *(const bf16x8*)(qp + ((size_t)bh * S_C + s0 + wave * 32 + qt * 16 + l15) * DH_C
                                          + kk * 32 + quad * 8);

    float m_i[2] = {-1e30f, -1e30f}, l_i[2] = {0.f, 0.f};
    f32x4 Oacc[2][4] = {};                // [qt][dt]  O^T[d][qrow]
    bf16* pw = p_lds + wave * (32 * 40);

    for (int kt = 0; kt < 8; ++kt) {
        __syncthreads();   // previous tile fully consumed
        const bf16* kbase = ksp + ((size_t)bh * S_C + kt * 128) * DH_C;
        const bf16* vbase = vTp + (size_t)bh * DH_C * S_C + kt * 128;
        for (int i = 0; i < 4; ++i) {
            int q = tid + i * 256;
            int r = q >> 3, c = q & 7;                     // K: 128 rows x 8 chunks
            gl_lds16(kbase + r * DH_C + (c ^ (r & 7)) * 8, k_lds + q * 8);
            int d = q >> 4, c16 = q & 15;                  // vT: 64 rows x 16 chunks
            gl_lds16(vbase + (size_t)d * S_C + ((c16 ^ (d & 7)) * 8), vT_lds + q * 8);
        }
        __syncthreads();   // loads drained (vmcnt) + madd visible (kt==0)

        // --- S^T tiles: 8 key-tiles x 2 q-tiles ---
        f32x4 sacc[8][2] = {};
        for (int kk = 0; kk < 2; ++kk) {
            const int ch = ((kk * 4 + quad) ^ swz) * 8;
            for (int ct = 0; ct < 8; ++ct) {
                bf16x8 kf = *(const bf16x8*)(k_lds + (ct * 16 + l15) * 64 + ch);
                sacc[ct][0] = __builtin_amdgcn_mfma_f32_16x16x32_bf16(kf, qf[0][kk], sacc[ct][0], 0, 0, 0);
                sacc[ct][1] = __builtin_amdgcn_mfma_f32_16x16x32_bf16(kf, qf[1][kk], sacc[ct][1], 0, 0, 0);
            }
        }
        // scale + mask (one FMA per element)
        for (int ct = 0; ct < 8; ++ct) {
            f32x4 md = *(const f32x4*)(madd + kt * 128 + ct * 16 + quad * 4);
            for (int qt = 0; qt < 2; ++qt)
                for (int r = 0; r < 4; ++r)
                    sacc[ct][qt][r] = sacc[ct][qt][r] * SC2 + md[r];
        }
        // online softmax per q-tile (keys live in regs + across quads)
        float fac[2];
        for (int qt = 0; qt < 2; ++qt) {
            float tm = sacc[0][qt][0];
            for (int ct = 0; ct < 8; ++ct)
                for (int r = 0; r < 4; ++r) tm = fmaxf(tm, sacc[ct][qt][r]);
            tm = fmaxf(tm, __shfl_xor(tm, 16, 64));
            tm = fmaxf(tm, __shfl_xor(tm, 32, 64));
            float mn = fmaxf(m_i[qt], tm);
            fac[qt] = __builtin_amdgcn_exp2f(m_i[qt] - mn);
            m_i[qt] = mn;
            float ts = 0.f;
            for (int ct = 0; ct < 8; ++ct)
                for (int r = 0; r < 4; ++r) {
                    float p = __builtin_amdgcn_exp2f(sacc[ct][qt][r] - mn);
                    sacc[ct][qt][r] = p;
                    ts += p;
                }
            ts += __shfl_xor(ts, 16, 64);
            ts += __shfl_xor(ts, 32, 64);
            l_i[qt] = l_i[qt] * fac[qt] + ts;
            for (int dt = 0; dt < 4; ++dt)
                for (int r = 0; r < 4; ++r) Oacc[qt][dt][r] *= fac[qt];
        }
        // --- PV: chunk-wise P relayout (b64 writes, wave-private) + MFMA ---
        for (int c = 0; c < 4; ++c) {
            for (int qt = 0; qt < 2; ++qt)
                for (int half = 0; half < 2; ++half) {
                    bf16x4 pv = __builtin_convertvector(sacc[2 * c + half][qt], bf16x4);
                    *(bf16x4*)(pw + (qt * 16 + l15) * 40 + half * 16 + quad * 4) = pv;
                }
            bf16x8 pf0 = *(const bf16x8*)(pw + l15 * 40 + quad * 8);
            bf16x8 pf1 = *(const bf16x8*)(pw + (16 + l15) * 40 + quad * 8);
            for (int dt = 0; dt < 4; ++dt) {
                bf16x8 vf = *(const bf16x8*)(vT_lds + (dt * 16 + l15) * 128 + ((c * 4 + quad) ^ swz) * 8);
                Oacc[0][dt] = __builtin_amdgcn_mfma_f32_16x16x32_bf16(vf, pf0, Oacc[0][dt], 0, 0, 0);
                Oacc[1][dt] = __builtin_amdgcn_mfma_f32_16x16x32_bf16(vf, pf1, Oacc[1][dt], 0, 0, 0);
            }
        }
    }

    // epilogue: O^T frag col(n)=l15=qrow, row(m)=quad*4+r=d -> pack 4 features
    for (int qt = 0; qt < 2; ++qt) {
        float inv = 1.f / l_i[qt];
        int token = s0 + wave * 32 + qt * 16 + l15;
        for (int dt = 0; dt < 4; ++dt) {
            f32x4 o;
            for (int r = 0; r < 4; ++r) o[r] = Oacc[qt][dt][r] * inv;
            bf16x4 ob = __builtin_convertvector(o, bf16x4);
            *(bf16x4*)(hout + (size_t)(b * S_C + token) * HID_C + h * DH_C + dt * 16 + quad * 4) = ob;
        }
    }
}

// ----------------------------------------------------------------- launch ---
extern "C" void kernel_launch(void* const* d_in, const int* in_sizes, int n_in,
                              void* d_out, int out_size, void* d_ws, size_t ws_size,
                              hipStream_t stream) {
    const float* q_a  = (const float*)d_in[0];
    const float* k_a  = (const float*)d_in[1];
    const float* v_a  = (const float*)d_in[2];
    const float* q_b  = (const float*)d_in[3];
    const float* k_b  = (const float*)d_in[4];
    const float* v_b  = (const float*)d_in[5];
    const int*   mask = (const int*)  d_in[6];
    const float* Wa   = (const float*)d_in[7];
    const float* ba   = (const float*)d_in[8];
    const float* Wb   = (const float*)d_in[9];
    const float* bb   = (const float*)d_in[10];
    const float* Wo_a = (const float*)d_in[11];
    const float* bo_a = (const float*)d_in[12];
    const float* Wo_b = (const float*)d_in[13];
    const float* bo_b = (const float*)d_in[14];
    float* out = (float*)d_out;

    constexpr size_t ACT = (size_t)NTOK * HID_C;       // 4,194,304
    constexpr size_t W3  = 3 * (size_t)HID_C * HID_C;  // 3,145,728
    constexpr size_t W1  = (size_t)HID_C * HID_C;      // 1,048,576

    bf16* w = (bf16*)d_ws;
    bf16* bfa[6];
    for (int i = 0; i < 6; ++i) bfa[i] = w + (size_t)i * ACT;
    bf16* bfWa  = w + 6 * ACT;
    bf16* bfWb  = bfWa + W3;
    bf16* bfWoA = bfWb + W3;
    bf16* bfWoB = bfWoA + W1;
    bf16* qa_p  = bfWoB + W1;
    bf16* qb_p  = qa_p + ACT;
    bf16* ks_p  = qb_p + ACT;
    bf16* vTa   = ks_p + ACT;
    bf16* vTb   = vTa + ACT;
    bf16* ha    = vTb + ACT;
    bf16* hb    = ha + ACT;

    // 1) all fp32->bf16 converts in ONE launch
    CvtArgs ca;
    const float* srcs[10] = {q_a, k_a, v_a, q_b, k_b, v_b, Wa, Wb, Wo_a, Wo_b};
    bf16* dsts[10] = {bfa[0], bfa[1], bfa[2], bfa[3], bfa[4], bfa[5], bfWa, bfWb, bfWoA, bfWoB};
    int nblk[10] = {4096, 4096, 4096, 4096, 4096, 4096, 3072, 3072, 1024, 1024};
    int cum = 0;
    for (int i = 0; i < 10; ++i) { ca.src[i] = srcs[i]; ca.dst[i] = dsts[i]; ca.cum[i] = cum; cum += nblk[i]; }
    ca.cum[10] = cum;
    cvt_all<<<cum, 256, 0, stream>>>(ca);

    // 2) projections
    dim3 gg(HID_C / 128, NTOK / 128);  // (8, 32)
    gemm_bt<<<gg, 256, 0, stream>>>(bfa[0], bfWa,           nullptr, nullptr,
                                    ba,        nullptr, qa_p, 0);
    gemm_bt<<<gg, 256, 0, stream>>>(bfa[3], bfWb,           nullptr, nullptr,
                                    bb,        nullptr, qb_p, 0);
    gemm_bt<<<gg, 256, 0, stream>>>(bfa[1], bfWa + W1,      bfa[4],  bfWb + W1,
                                    ba + 1024, bb + 1024, ks_p, 0);   // ks = ka + kb
    gemm_bt<<<gg, 256, 0, stream>>>(bfa[2], bfWa + 2 * W1,  nullptr, nullptr,
                                    ba + 2048, nullptr, vTa, 1);
    gemm_bt<<<gg, 256, 0, stream>>>(bfa[5], bfWb + 2 * W1,  nullptr, nullptr,
                                    bb + 2048, nullptr, vTb, 1);

    // 3) fused attention, both streams in one launch (z)
    dim3 ga(S_C / 128, B_C * H_C, 2);  // (8, 64, 2)
    attn_fused<<<ga, 256, 0, stream>>>(qa_p, qb_p, ks_p, vTa, vTb, mask, ha, hb);

    // 4) output projections -> fp32 d_out (concatenated tuple)
    gemm_bt<<<gg, 256, 0, stream>>>(ha, bfWoA, nullptr, nullptr, bo_a, nullptr,
                                    (void*)out, 2);
    gemm_bt<<<gg, 256, 0, stream>>>(hb, bfWoB, nullptr, nullptr, bo_b, nullptr,
                                    (void*)(out + (size_t)NTOK * HID_C), 2);
}

// Round 3
// 348.663 us; speedup vs baseline: 1.6439x; 1.3756x over previous
//
#include <hip/hip_runtime.h>

// ---------------------------------------------------------------------------
// DisentangleMultiHeadedAttention on MI355X (gfx950), bf16 MFMA pipeline v3.
// B=4, S=1024, HID=1024, HEADS=16, DH=64.  N_TOK=4096.
// corr_a = qa (ka+kb)^T * scale ; corr_b = qb (ka+kb)^T * scale
//   => one fused ks = k_a@Wa1^T + k_b@Wb1^T (K=2048 GEMM).
// v3: batched GEMM launches (z=job -> 1280/512 blocks, ~3 blocks/CU overlap);
//     attention double-buffers K/V^T via global_load_lds and uses an
//     XCD-locality grid (x=bh so all consumers of one bh share an XCD L2);
//     softmax scale folded into Q-projection epilogue.
// ---------------------------------------------------------------------------

typedef __bf16 bf16;
typedef __bf16 bf16x4 __attribute__((ext_vector_type(4)));
typedef __bf16 bf16x8 __attribute__((ext_vector_type(8)));
typedef float  f32x4  __attribute__((ext_vector_type(4)));

#define HID_C   1024
#define S_C     1024
#define B_C     4
#define H_C     16
#define DH_C    64
#define NTOK    4096

__device__ __forceinline__ void gl_lds16(const bf16* g, bf16* l) {
    __builtin_amdgcn_global_load_lds(
        (const __attribute__((address_space(1))) void*)g,
        (__attribute__((address_space(3))) void*)l, 16, 0, 0);
}

// ---------------------------------------------------------------- convert ---
struct CvtArgs {
    const float* src[10];
    bf16*        dst[10];
    int          cum[11];   // cumulative block counts (1024 elems per block)
};

__global__ __launch_bounds__(256) void cvt_all(CvtArgs a) {
    int blk = blockIdx.x;
    int seg = 0;
    while (blk >= a.cum[seg + 1]) ++seg;
    int i = ((blk - a.cum[seg]) * 256 + threadIdx.x) * 4;
    f32x4 v = *(const f32x4*)(a.src[seg] + i);
    *(bf16x4*)(a.dst[seg] + i) = __builtin_convertvector(v, bf16x4);
}

// ------------------------------------------------------------------- GEMM ---
// C[m,n] = (sum_k A[m,k]*W[n,k] (+2nd pair) + bias) * scale
// 128x128 tile, BK=64, global_load_lds(16B), XOR-swizzled LDS chunks.
// Batched: blockIdx.z selects the job.  ~3 blocks/CU co-resident.
// mode 0: bf16 out [B,H,S,DH] | mode 1: bf16 out [B,H,DH,S] | mode 2: f32 out.
struct GemmJob {
    const bf16* A1; const bf16* W1;
    const bf16* A2; const bf16* W2;
    const float* bias1; const float* bias2;
    void* out; int mode; float scale;
};
struct GemmBatch { GemmJob j[5]; };

__global__ __launch_bounds__(256, 3)
void gemm_bt(GemmBatch gb) {
    const GemmJob jb = gb.j[blockIdx.z];
    const int K = HID_C;
    __shared__ bf16 a_lds[128 * 64];
    __shared__ bf16 w_lds[128 * 64];

    const int tid  = threadIdx.x;
    const int wave = tid >> 6, lane = tid & 63;
    const int quad = lane >> 4, l15 = lane & 15;
    const int swz  = l15 & 7;
    const int row0 = blockIdx.y * 128;
    const int col0 = blockIdx.x * 128;
    const int wr = (wave >> 1) * 64;
    const int wc = (wave & 1) * 64;

    f32x4 acc[4][4] = {};

    const int nkb = jb.A2 ? 32 : 16;
    for (int kb = 0; kb < nkb; ++kb) {
        const bf16* A = (kb < 16) ? jb.A1 : jb.A2;
        const bf16* W = (kb < 16) ? jb.W1 : jb.W2;
        const int k0 = (kb & 15) * 64;
        __syncthreads();
        for (int i = 0; i < 4; ++i) {
            int q = tid + i * 256;
            int r = q >> 3, c = q & 7;
            int gch = c ^ (r & 7);
            gl_lds16(A + (size_t)(row0 + r) * K + k0 + gch * 8, a_lds + q * 8);
            gl_lds16(W + (size_t)(col0 + r) * K + k0 + gch * 8, w_lds + q * 8);
        }
        __syncthreads();
        for (int kk = 0; kk < 2; ++kk) {
            const int ch = ((kk * 4 + quad) ^ swz) * 8;
            bf16x8 af[4], bw[4];
            for (int mi = 0; mi < 4; ++mi)
                af[mi] = *(const bf16x8*)(a_lds + (wr + mi * 16 + l15) * 64 + ch);
            for (int ni = 0; ni < 4; ++ni)
                bw[ni] = *(const bf16x8*)(w_lds + (wc + ni * 16 + l15) * 64 + ch);
            for (int mi = 0; mi < 4; ++mi)
                for (int ni = 0; ni < 4; ++ni)
                    acc[mi][ni] = __builtin_amdgcn_mfma_f32_16x16x32_bf16(af[mi], bw[ni], acc[mi][ni], 0, 0, 0);
        }
    }

    // epilogue.  C layout per 16x16 tile: col(n) = lane&15, row(m) = quad*4+reg.
    for (int mi = 0; mi < 4; ++mi) {
        for (int ni = 0; ni < 4; ++ni) {
            int colg = col0 + wc + ni * 16 + l15;
            float bv = jb.bias1 ? jb.bias1[colg] : 0.f;
            if (jb.bias2) bv += jb.bias2[colg];
            for (int r = 0; r < 4; ++r) {
                int rowg = row0 + wr + mi * 16 + quad * 4 + r;
                float v = (acc[mi][ni][r] + bv) * jb.scale;
                if (jb.mode == 2) {
                    ((float*)jb.out)[(size_t)rowg * HID_C + colg] = v;
                } else {
                    int b = rowg >> 10, s = rowg & 1023;
                    int h = colg >> 6,  d = colg & 63;
                    size_t idx = (jb.mode == 0)
                        ? ((size_t)((b * H_C + h) * S_C + s) * DH_C + d)
                        : ((size_t)((b * H_C + h) * DH_C + d) * S_C + s);
                    ((bf16*)jb.out)[idx] = (bf16)v;
                }
            }
        }
    }
}

// -------------------------------------------------------------- attention ---
// S^T formulation: S^T = K Q^T (A=K, B=Q), O^T = V^T P^T (A=V^T, B=P^T).
// Q pre-scaled by 1/sqrt(2*DH)*log2(e) in its projection; exp2 softmax.
// Block = 128 q-rows x one (b,h) x one stream; 4 waves x 32 rows.
// Double-buffered K/V^T staging: stage(kt+1) issued right after the barrier,
// so the vmcnt drain at the next barrier waits on loads that have been in
// flight for a whole compute phase.  Grid (bh, q, z): id%8 = bh%8 pins all
// 16 consumers of one bh's K/V to one XCD -> K/V tiles stay in that L2.
__global__ __launch_bounds__(256, 2)
void attn_fused(const bf16* __restrict__ qp_a, const bf16* __restrict__ qp_b,
                const bf16* __restrict__ ksp,
                const bf16* __restrict__ vT_a, const bf16* __restrict__ vT_b,
                const int* __restrict__ mask,
                bf16* __restrict__ ho_a, bf16* __restrict__ ho_b) {
    __shared__ bf16  k_lds[2][128 * 64];   // [key][d], XOR-swizzled chunks
    __shared__ bf16  vT_lds[2][64 * 128];  // [d][key], XOR-swizzled chunks
    __shared__ float madd[1024];           // 0 or -1e9 per key
    __shared__ bf16  p_lds[4 * 32 * 40];   // per-wave [qrow][key32] pad->40

    const int tid  = threadIdx.x;
    const int wave = tid >> 6, lane = tid & 63;
    const int quad = lane >> 4, l15 = lane & 15;
    const int swz  = l15 & 7;
    const int bh = blockIdx.x;             // XCD-locality: bh fastest
    const int b  = bh >> 4, h = bh & 15;
    const int s0 = blockIdx.y * 128;
    const bf16* qp   = blockIdx.z ? qp_b : qp_a;
    const bf16* vTp  = blockIdx.z ? vT_b : vT_a;
    bf16*       hout = blockIdx.z ? ho_b : ho_a;

    // mask -> additive table
    {
        int4 mv = *(const int4*)(mask + b * S_C + tid * 4);
        f32x4 md;
        md[0] = mv.x ? 0.f : -1e9f;
        md[1] = mv.y ? 0.f : -1e9f;
        md[2] = mv.z ? 0.f : -1e9f;
        md[3] = mv.w ? 0.f : -1e9f;
        *(f32x4*)(madd + tid * 4) = md;
    }

    // Q B-fragments from global, live in registers all kernel (pre-scaled)
    bf16x8 qf[2][2];
    for (int qt = 0; qt < 2; ++qt)
        for (int kk = 0; kk < 2; ++kk)
            qf[qt][kk] = *(const bf16x8*)(qp + ((size_t)bh * S_C + s0 + wave * 32 + qt * 16 + l15) * DH_C
                                          + kk * 32 + quad * 8);

    const bf16* kbase0 = ksp + (size_t)bh * S_C * DH_C;
    const bf16* vbase0 = vTp + (size_t)bh * DH_C * S_C;
    auto stage = [&](int kt, int buf) {
        const bf16* kb = kbase0 + kt * 128 * DH_C;
        const bf16* vb = vbase0 + kt * 128;
        for (int i = 0; i < 4; ++i) {
            int q = tid + i * 256;
            int r = q >> 3, c = q & 7;
            gl_lds16(kb + r * DH_C + ((c ^ (r & 7)) * 8), &k_lds[buf][q * 8]);
            int d = q >> 4, c16 = q & 15;
            gl_lds16(vb + (size_t)d * S_C + ((c16 ^ (d & 7)) * 8), &vT_lds[buf][q * 8]);
        }
    };

    float m_i[2] = {-1e30f, -1e30f}, l_i[2] = {0.f, 0.f};
    f32x4 Oacc[2][4] = {};                 // [qt][dt]  O^T[d][qrow]
    bf16* pw = p_lds + wave * (32 * 40);

    stage(0, 0);
    for (int kt = 0; kt < 8; ++kt) {
        const int cur = kt & 1;
        __syncthreads();                   // drains stage(kt); frees buf 1-cur
        if (kt < 7) stage(kt + 1, 1 - cur);
        const bf16* kl = k_lds[cur];
        const bf16* vl = vT_lds[cur];

        // --- S^T tiles: 8 key-tiles x 2 q-tiles ---
        f32x4 sacc[8][2] = {};
        for (int kk = 0; kk < 2; ++kk) {
            const int ch = ((kk * 4 + quad) ^ swz) * 8;
            for (int ct = 0; ct < 8; ++ct) {
                bf16x8 kf = *(const bf16x8*)(kl + (ct * 16 + l15) * 64 + ch);
                sacc[ct][0] = __builtin_amdgcn_mfma_f32_16x16x32_bf16(kf, qf[0][kk], sacc[ct][0], 0, 0, 0);
                sacc[ct][1] = __builtin_amdgcn_mfma_f32_16x16x32_bf16(kf, qf[1][kk], sacc[ct][1], 0, 0, 0);
            }
        }
        // mask add (scale already folded into Q)
        for (int ct = 0; ct < 8; ++ct) {
            f32x4 md = *(const f32x4*)(madd + kt * 128 + ct * 16 + quad * 4);
            for (int qt = 0; qt < 2; ++qt)
                for (int r = 0; r < 4; ++r)
                    sacc[ct][qt][r] += md[r];
        }
        // online softmax per q-tile (log2 domain)
        float fac[2];
        for (int qt = 0; qt < 2; ++qt) {
            float tm = sacc[0][qt][0];
            for (int ct = 0; ct < 8; ++ct)
                for (int r = 0; r < 4; ++r) tm = fmaxf(tm, sacc[ct][qt][r]);
            tm = fmaxf(tm, __shfl_xor(tm, 16, 64));
            tm = fmaxf(tm, __shfl_xor(tm, 32, 64));
            float mn = fmaxf(m_i[qt], tm);
            fac[qt] = __builtin_amdgcn_exp2f(m_i[qt] - mn);
            m_i[qt] = mn;
            float ts = 0.f;
            for (int ct = 0; ct < 8; ++ct)
                for (int r = 0; r < 4; ++r) {
                    float p = __builtin_amdgcn_exp2f(sacc[ct][qt][r] - mn);
                    sacc[ct][qt][r] = p;
                    ts += p;
                }
            ts += __shfl_xor(ts, 16, 64);
            ts += __shfl_xor(ts, 32, 64);
            l_i[qt] = l_i[qt] * fac[qt] + ts;
            for (int dt = 0; dt < 4; ++dt)
                for (int r = 0; r < 4; ++r) Oacc[qt][dt][r] *= fac[qt];
        }
        // --- PV: chunk-wise P relayout (b64 writes, wave-private) + MFMA ---
        for (int c = 0; c < 4; ++c) {
            for (int qt = 0; qt < 2; ++qt)
                for (int half = 0; half < 2; ++half) {
                    bf16x4 pv = __builtin_convertvector(sacc[2 * c + half][qt], bf16x4);
                    *(bf16x4*)(pw + (qt * 16 + l15) * 40 + half * 16 + quad * 4) = pv;
                }
            bf16x8 pf0 = *(const bf16x8*)(pw + l15 * 40 + quad * 8);
            bf16x8 pf1 = *(const bf16x8*)(pw + (16 + l15) * 40 + quad * 8);
            for (int dt = 0; dt < 4; ++dt) {
                bf16x8 vf = *(const bf16x8*)(vl + (dt * 16 + l15) * 128 + ((c * 4 + quad) ^ swz) * 8);
                Oacc[0][dt] = __builtin_amdgcn_mfma_f32_16x16x32_bf16(vf, pf0, Oacc[0][dt], 0, 0, 0);
                Oacc[1][dt] = __builtin_amdgcn_mfma_f32_16x16x32_bf16(vf, pf1, Oacc[1][dt], 0, 0, 0);
            }
        }
    }

    // epilogue: O^T frag col(n)=l15=qrow, row(m)=quad*4+r=d -> pack 4 features
    for (int qt = 0; qt < 2; ++qt) {
        float inv = 1.f / l_i[qt];
        int token = s0 + wave * 32 + qt * 16 + l15;
        for (int dt = 0; dt < 4; ++dt) {
            f32x4 o;
            for (int r = 0; r < 4; ++r) o[r] = Oacc[qt][dt][r] * inv;
            bf16x4 ob = __builtin_convertvector(o, bf16x4);
            *(bf16x4*)(hout + (size_t)(b * S_C + token) * HID_C + h * DH_C + dt * 16 + quad * 4) = ob;
        }
    }
}

// ----------------------------------------------------------------- launch ---
extern "C" void kernel_launch(void* const* d_in, const int* in_sizes, int n_in,
                              void* d_out, int out_size, void* d_ws, size_t ws_size,
                              hipStream_t stream) {
    const float* q_a  = (const float*)d_in[0];
    const float* k_a  = (const float*)d_in[1];
    const float* v_a  = (const float*)d_in[2];
    const float* q_b  = (const float*)d_in[3];
    const float* k_b  = (const float*)d_in[4];
    const float* v_b  = (const float*)d_in[5];
    const int*   mask = (const int*)  d_in[6];
    const float* Wa   = (const float*)d_in[7];
    const float* ba   = (const float*)d_in[8];
    const float* Wb   = (const float*)d_in[9];
    const float* bb   = (const float*)d_in[10];
    const float* Wo_a = (const float*)d_in[11];
    const float* bo_a = (const float*)d_in[12];
    const float* Wo_b = (const float*)d_in[13];
    const float* bo_b = (const float*)d_in[14];
    float* out = (float*)d_out;

    constexpr size_t ACT = (size_t)NTOK * HID_C;       // 4,194,304
    constexpr size_t W3  = 3 * (size_t)HID_C * HID_C;  // 3,145,728
    constexpr size_t W1  = (size_t)HID_C * HID_C;      // 1,048,576
    // softmax scale * log2(e), folded into Q projections
    const float SC2 = 0.08838834764831845f * 1.4426950408889634f;

    bf16* w = (bf16*)d_ws;
    bf16* bfa[6];
    for (int i = 0; i < 6; ++i) bfa[i] = w + (size_t)i * ACT;
    bf16* bfWa  = w + 6 * ACT;
    bf16* bfWb  = bfWa + W3;
    bf16* bfWoA = bfWb + W3;
    bf16* bfWoB = bfWoA + W1;
    bf16* qa_p  = bfWoB + W1;
    bf16* qb_p  = qa_p + ACT;
    bf16* ks_p  = qb_p + ACT;
    bf16* vTa   = ks_p + ACT;
    bf16* vTb   = vTa + ACT;
    bf16* ha    = vTb + ACT;
    bf16* hb    = ha + ACT;

    // 1) all fp32->bf16 converts in ONE launch
    CvtArgs ca;
    const float* srcs[10] = {q_a, k_a, v_a, q_b, k_b, v_b, Wa, Wb, Wo_a, Wo_b};
    bf16* dsts[10] = {bfa[0], bfa[1], bfa[2], bfa[3], bfa[4], bfa[5], bfWa, bfWb, bfWoA, bfWoB};
    int nblk[10] = {4096, 4096, 4096, 4096, 4096, 4096, 3072, 3072, 1024, 1024};
    int cum = 0;
    for (int i = 0; i < 10; ++i) { ca.src[i] = srcs[i]; ca.dst[i] = dsts[i]; ca.cum[i] = cum; cum += nblk[i]; }
    ca.cum[10] = cum;
    cvt_all<<<cum, 256, 0, stream>>>(ca);

    // 2) all 5 projections in ONE launch (z=job; ks first: longest job's
    //    blocks dispatch earliest so its tail overlaps the others)
    GemmBatch g1;
    g1.j[0] = { bfa[1], bfWa + W1,     bfa[4], bfWb + W1, ba + 1024, bb + 1024, ks_p, 0, 1.f  };
    g1.j[1] = { bfa[0], bfWa,          nullptr, nullptr,  ba,        nullptr,   qa_p, 0, SC2 };
    g1.j[2] = { bfa[3], bfWb,          nullptr, nullptr,  bb,        nullptr,   qb_p, 0, SC2 };
    g1.j[3] = { bfa[2], bfWa + 2 * W1, nullptr, nullptr,  ba + 2048, nullptr,   vTa,  1, 1.f  };
    g1.j[4] = { bfa[5], bfWb + 2 * W1, nullptr, nullptr,  bb + 2048, nullptr,   vTb,  1, 1.f  };
    gemm_bt<<<dim3(HID_C / 128, NTOK / 128, 5), 256, 0, stream>>>(g1);

    // 3) fused attention, both streams, XCD-locality grid (bh fastest)
    dim3 ga(B_C * H_C, S_C / 128, 2);  // (64, 8, 2)
    attn_fused<<<ga, 256, 0, stream>>>(qa_p, qb_p, ks_p, vTa, vTb, mask, ha, hb);

    // 4) both output projections in ONE launch -> fp32 d_out
    GemmBatch g2;
    g2.j[0] = { ha, bfWoA, nullptr, nullptr, bo_a, nullptr, (void*)out, 2, 1.f };
    g2.j[1] = { hb, bfWoB, nullptr, nullptr, bo_b, nullptr,
                (void*)(out + (size_t)NTOK * HID_C), 2, 1.f };
    g2.j[2] = g2.j[0]; g2.j[3] = g2.j[0]; g2.j[4] = g2.j[0];  // unused
    gemm_bt<<<dim3(HID_C / 128, NTOK / 128, 2), 256, 0, stream>>>(g2);
}